// Round 7
// baseline (476.868 us; speedup 1.0000x reference)
//
#include <hip/hip_runtime.h>
#include <math.h>

#define T_N 2048
#define H_N 2048
#define E_N 32
#define I_N 512
#define NA_MOE (T_N*4)        // 8192 routed assignments
#define NA_ALL (NA_MOE + T_N) // + shared-expert rows = 10240
#define BM 256
#define BK 32
#define MAXT 72               // sum ceil(cnt/256) <= 64 routed + 8 shared
#define PART_FLOATS 10485760ull  // 10240*1024 per k-half

typedef short s16x8 __attribute__((ext_vector_type(8)));
typedef float f32x4 __attribute__((ext_vector_type(4)));

__device__ inline short f2bf(float f){
    unsigned int u = __float_as_uint(f);
    u = (u + 0x7fffu + ((u >> 16) & 1u)) >> 16;
    return (short)u;
}
__device__ inline float bf2f(short s){
    return __uint_as_float(((unsigned int)(unsigned short)s) << 16);
}
__device__ inline s16x8 cvt8(float4 f0, float4 f1){
    s16x8 v;
    v[0]=f2bf(f0.x); v[1]=f2bf(f0.y); v[2]=f2bf(f0.z); v[3]=f2bf(f0.w);
    v[4]=f2bf(f1.x); v[5]=f2bf(f1.y); v[6]=f2bf(f1.z); v[7]=f2bf(f1.w);
    return v;
}

// ---------------- cast x (fp32 -> bf16) ----------------
__global__ __launch_bounds__(256) void cast_x_kernel(const float* __restrict__ x,
                                                     short* __restrict__ xbf){
    size_t i = (size_t)(blockIdx.x * 256 + threadIdx.x) * 8;
    float4 a = *(const float4*)(x + i);
    float4 b = *(const float4*)(x + i + 4);
    *(s16x8*)(xbf + i) = cvt8(a, b);
}

// ---------------- router: logits (fp64 acc), softmax, top4, shared gate ----------------
__global__ __launch_bounds__(64) void router_kernel(
    const float* __restrict__ x, const float* __restrict__ Wr,
    const float* __restrict__ Wsgate,
    float* __restrict__ logits_out, int* __restrict__ tidx, float* __restrict__ tw,
    int* __restrict__ perm, float* __restrict__ wgt, int* __restrict__ counts)
{
    const int t = blockIdx.x, lane = threadIdx.x;
    const float* xr = x + (size_t)t * H_N;
    float xv[32];
    #pragma unroll
    for (int i = 0; i < 32; i++) xv[i] = xr[i*64 + lane];
    __shared__ float lg[34];
    for (int e = 0; e < 33; e++){
        const float* wr = (e < 32) ? (Wr + (size_t)e * H_N) : Wsgate;
        double s = 0.0;
        #pragma unroll
        for (int i = 0; i < 32; i++) s += (double)xv[i] * (double)wr[i*64 + lane];
        #pragma unroll
        for (int o = 32; o > 0; o >>= 1) s += __shfl_down(s, o);
        if (lane == 0) lg[e] = (float)s;
    }
    __syncthreads();
    if (lane < 32) logits_out[(size_t)t*32 + lane] = lg[lane];
    if (lane == 0){
        float m = lg[0];
        for (int e = 1; e < 32; e++) m = fmaxf(m, lg[e]);
        unsigned mask = 0; int sel[4]; float sv[4]; float s4 = 0.f;
        for (int k = 0; k < 4; k++){
            int best = -1; float bv = -1e30f;
            for (int e = 0; e < 32; e++)
                if (!((mask >> e) & 1u) && lg[e] > bv){ bv = lg[e]; best = e; }
            mask |= 1u << best; sel[k] = best;
            float p = expf(lg[best] - m); sv[k] = p; s4 += p;
        }
        for (int k = 0; k < 4; k++){
            tidx[t*4 + k] = sel[k];
            tw[t*4 + k]   = sv[k] / s4;
            atomicAdd(&counts[sel[k]], 1);
        }
        perm[NA_MOE + t] = t;                       // shared expert row
        wgt[NA_MOE + t]  = 1.f / (1.f + expf(-lg[32]));
    }
}

// ---------------- scan: offsets + worklist (shared expert first) ----------------
// ctrl ints: [0..63] counts, [64..127] cursors, [128..191] eoff,
//            [192..255] ecnt, [256] ntiles, [260..331] worklist
__global__ void scan_kernel(int* ctrl){
    if (threadIdx.x == 0){
        int* counts = ctrl; int* eoff = ctrl + 128; int* ecnt = ctrl + 192;
        int acc = 0;
        for (int e = 0; e < 32; e++){ eoff[e] = acc; ecnt[e] = counts[e]; acc += counts[e]; }
        eoff[32] = NA_MOE; ecnt[32] = T_N;
        int nt = 0;
        for (int m = 0; m * BM < T_N; m++) ctrl[260 + nt++] = (32 << 16) | m;   // shared first
        for (int e = 0; e < 32; e++){
            int c = ecnt[e];
            for (int m = 0; m * BM < c; m++) ctrl[260 + nt++] = (e << 16) | m;
        }
        ctrl[256] = nt;
    }
    if (threadIdx.x < 64) ctrl[64 + threadIdx.x] = 0;  // cursors
}

// ---------------- scatter tokens into per-expert lists ----------------
__global__ __launch_bounds__(256) void scatter_kernel(
    const int* __restrict__ tidx, const float* __restrict__ tw,
    int* __restrict__ perm, float* __restrict__ wgt, int* __restrict__ apos,
    int* ctrl)
{
    int t = blockIdx.x * 256 + threadIdx.x;
    if (t >= T_N) return;
    const int* eoff = ctrl + 128; int* cursor = ctrl + 64;
    for (int k = 0; k < 4; k++){
        int e = tidx[t*4 + k];
        int pos = eoff[e] + atomicAdd(&cursor[e], 1);
        perm[pos] = t; wgt[pos] = tw[t*4 + k]; apos[t*4 + k] = pos;
    }
}

// ---------------- GEMM1: 256x(32g+32u) tile, K-split, LDS dbuf depth-2 ----------------
// KS=2: writes fp32 partials (kh planes); KS=1: writes hact directly.
template<int KS>
__global__ __launch_bounds__(256, 3) void gemm1_kernel(
    const short* __restrict__ xbf,
    const float* __restrict__ Wg, const float* __restrict__ Wu,
    const float* __restrict__ Wsg, const float* __restrict__ Wsu,
    const int* __restrict__ perm, const int* __restrict__ ctrl,
    short* __restrict__ hact, float* __restrict__ part)
{
    const int bid  = blockIdx.x;
    const int tile = bid / (16*KS);
    if (tile >= ctrl[256]) return;
    const int sub = bid % (16*KS);
    const int nb  = (KS==2) ? (sub >> 1) : sub;
    const int kh  = (KS==2) ? (sub & 1) : 0;
    const int KH  = H_N / KS;
    const int wrk = ctrl[260 + tile];
    const int e   = wrk >> 16;
    const int m0  = (wrk & 0xffff) << 8;
    const int cnt = ctrl[192 + e];
    const int off = ctrl[128 + e];
    const int n0  = nb * 32;

    __shared__ s16x8 lsA[2][4*256];   // [buf][kc][row]
    __shared__ s16x8 lsBg[2][4*32];
    __shared__ s16x8 lsBu[2][4*32];

    const int tid = threadIdx.x;
    // A: one thread per row, 4 k-chunks (64B of the row)
    const short* arow = nullptr;
    if (m0 + tid < cnt) arow = xbf + (size_t)perm[off + m0 + tid] * H_N + kh*KH;
    // B: tid<128 -> gate, else up; lane-contiguous chunk map (rb=t&31, kcb=t>>5)
    const int tb  = tid & 127;
    const int rb  = tb & 31, kcb = tb >> 5;
    const float* brow;
    if (e < 32) brow = ((tid < 128) ? Wg : Wu) + ((size_t)e*I_N + n0 + rb)*H_N + kh*KH + kcb*8;
    else        brow = ((tid < 128) ? Wsg : Wsu) + (size_t)(n0 + rb)*H_N + kh*KH + kcb*8;

    const int wid = tid >> 6, lane = tid & 63;
    const int wm = wid;                 // 4 waves stacked in M
    const int kg = lane >> 4, l15 = lane & 15;

    f32x4 accg[4][2], accu[4][2];
    #pragma unroll
    for (int a = 0; a < 4; a++)
        #pragma unroll
        for (int b = 0; b < 2; b++)
            #pragma unroll
            for (int j = 0; j < 4; j++){ accg[a][b][j] = 0.f; accu[a][b][j] = 0.f; }

    // prologue: k-step 0 -> lds[0]
    {
        s16x8 a[4] = {{0},{0},{0},{0}};
        if (arow){
            #pragma unroll
            for (int kc = 0; kc < 4; kc++) a[kc] = *(const s16x8*)(arow + kc*8);
        }
        #pragma unroll
        for (int kc = 0; kc < 4; kc++) lsA[0][kc*256 + tid] = a[kc];
        float4 f0 = *(const float4*)(brow);
        float4 f1 = *(const float4*)(brow + 4);
        ((tid < 128) ? lsBg[0] : lsBu[0])[kcb*32 + rb] = cvt8(f0, f1);
    }
    // pending: k-step 1
    s16x8 pa[4] = {{0},{0},{0},{0}};
    if (arow){
        #pragma unroll
        for (int kc = 0; kc < 4; kc++) pa[kc] = *(const s16x8*)(arow + BK + kc*8);
    }
    float4 pf0 = *(const float4*)(brow + BK);
    float4 pf1 = *(const float4*)(brow + BK + 4);

    int cur = 0;
    for (int k0 = 0; k0 < KH; k0 += BK){
        __syncthreads();
        s16x8 na[4] = {{0},{0},{0},{0}};
        float4 nf0{}, nf1{};
        if (k0 + 2*BK < KH){
            const int kn = k0 + 2*BK;
            if (arow){
                #pragma unroll
                for (int kc = 0; kc < 4; kc++) na[kc] = *(const s16x8*)(arow + kn + kc*8);
            }
            nf0 = *(const float4*)(brow + kn);
            nf1 = *(const float4*)(brow + kn + 4);
        }
        if (k0 + BK < KH){
            const int nbuf = cur ^ 1;
            #pragma unroll
            for (int kc = 0; kc < 4; kc++) lsA[nbuf][kc*256 + tid] = pa[kc];
            ((tid < 128) ? lsBg[nbuf] : lsBu[nbuf])[kcb*32 + rb] = cvt8(pf0, pf1);
        }
        #pragma unroll
        for (int mf = 0; mf < 4; mf++){
            s16x8 a = lsA[cur][kg*256 + wm*64 + mf*16 + l15];
            #pragma unroll
            for (int nf = 0; nf < 2; nf++){
                s16x8 bg = lsBg[cur][kg*32 + nf*16 + l15];
                s16x8 bu = lsBu[cur][kg*32 + nf*16 + l15];
                accg[mf][nf] = __builtin_amdgcn_mfma_f32_16x16x32_bf16(a, bg, accg[mf][nf], 0, 0, 0);
                accu[mf][nf] = __builtin_amdgcn_mfma_f32_16x16x32_bf16(a, bu, accu[mf][nf], 0, 0, 0);
            }
        }
        #pragma unroll
        for (int kc = 0; kc < 4; kc++) pa[kc] = na[kc];
        pf0 = nf0; pf1 = nf1;
        cur ^= 1;
    }

    if (KS == 2){
        float* pb = part + (size_t)kh * PART_FLOATS;
        #pragma unroll
        for (int mf = 0; mf < 4; mf++){
            #pragma unroll
            for (int j = 0; j < 4; j++){
                int row = m0 + wm*64 + mf*16 + kg*4 + j;
                if (row < cnt){
                    float* pr = pb + (size_t)(off + row) * 1024 + n0;
                    #pragma unroll
                    for (int nf = 0; nf < 2; nf++){
                        __builtin_nontemporal_store(accg[mf][nf][j], pr + nf*16 + l15);
                        __builtin_nontemporal_store(accu[mf][nf][j], pr + 512 + nf*16 + l15);
                    }
                }
            }
        }
    } else {
        #pragma unroll
        for (int mf = 0; mf < 4; mf++){
            #pragma unroll
            for (int j = 0; j < 4; j++){
                int row = m0 + wm*64 + mf*16 + kg*4 + j;
                if (row < cnt){
                    #pragma unroll
                    for (int nf = 0; nf < 2; nf++){
                        int col = n0 + nf*16 + l15;
                        float g = accg[mf][nf][j], u = accu[mf][nf][j];
                        float h = g / (1.f + expf(-g)) * u;
                        hact[(size_t)(off + row) * I_N + col] = f2bf(h);
                    }
                }
            }
        }
    }
}

// ---------------- fixup: hact = silu(g0+g1)*(u0+u1), bf16 ----------------
__global__ __launch_bounds__(256) void fixup_kernel(const float* __restrict__ part,
                                                    short* __restrict__ hact){
    size_t base = ((size_t)blockIdx.x * 256 + threadIdx.x) * 8;
    int row = (int)(base >> 9);
    int c   = (int)(base & 511);
    const float* pg0 = part + (size_t)row * 1024 + c;
    const float* pg1 = pg0 + PART_FLOATS;
    float g[8], u[8];
    {
        f32x4 a0 = __builtin_nontemporal_load((const f32x4*)pg0);
        f32x4 a1 = __builtin_nontemporal_load((const f32x4*)(pg0 + 4));
        f32x4 b0 = __builtin_nontemporal_load((const f32x4*)pg1);
        f32x4 b1 = __builtin_nontemporal_load((const f32x4*)(pg1 + 4));
        #pragma unroll
        for (int j = 0; j < 4; j++){ g[j] = a0[j] + b0[j]; g[4+j] = a1[j] + b1[j]; }
    }
    {
        f32x4 a0 = __builtin_nontemporal_load((const f32x4*)(pg0 + 512));
        f32x4 a1 = __builtin_nontemporal_load((const f32x4*)(pg0 + 516));
        f32x4 b0 = __builtin_nontemporal_load((const f32x4*)(pg1 + 512));
        f32x4 b1 = __builtin_nontemporal_load((const f32x4*)(pg1 + 516));
        #pragma unroll
        for (int j = 0; j < 4; j++){ u[j] = a0[j] + b0[j]; u[4+j] = a1[j] + b1[j]; }
    }
    s16x8 v;
    #pragma unroll
    for (int j = 0; j < 8; j++){
        float h = g[j] / (1.f + expf(-g[j])) * u[j];
        v[j] = f2bf(h);
    }
    *(s16x8*)(hact + (size_t)row * I_N + c) = v;
}

// ---------------- GEMM2: 256x64 tile, LDS dbuf depth-2 ----------------
template<int USE_Y>
__global__ __launch_bounds__(256, 3) void gemm2_kernel(
    const short* __restrict__ hact,
    const float* __restrict__ Wd, const float* __restrict__ Wsd,
    const int* __restrict__ perm, const float* __restrict__ wgt,
    const int* __restrict__ ctrl, float* __restrict__ out, short* __restrict__ y)
{
    const int tile = blockIdx.x >> 5;
    if (tile >= ctrl[256]) return;
    const int nb  = blockIdx.x & 31;
    const int wrk = ctrl[260 + tile];
    const int e   = wrk >> 16;
    const int m0  = (wrk & 0xffff) << 8;
    const int cnt = ctrl[192 + e];
    const int off = ctrl[128 + e];
    const int n0  = nb * 64;

    __shared__ s16x8 lsA[2][4*256];
    __shared__ s16x8 lsB[2][4*64];

    const int tid = threadIdx.x;
    const short* arow = nullptr;
    if (m0 + tid < cnt) arow = hact + (size_t)(off + m0 + tid) * I_N;
    const int rb = tid & 63, kcb = tid >> 6;
    const float* brow = (e < 32) ? (Wd  + ((size_t)e * H_N + n0 + rb) * I_N + kcb*8)
                                 : (Wsd + (size_t)(n0 + rb) * I_N + kcb*8);

    const int wid = tid >> 6, lane = tid & 63;
    const int wm = wid;
    const int kg = lane >> 4, l15 = lane & 15;

    f32x4 acc[4][4];
    #pragma unroll
    for (int a = 0; a < 4; a++)
        #pragma unroll
        for (int b = 0; b < 4; b++)
            #pragma unroll
            for (int j = 0; j < 4; j++) acc[a][b][j] = 0.f;

    {
        s16x8 a[4] = {{0},{0},{0},{0}};
        if (arow){
            #pragma unroll
            for (int kc = 0; kc < 4; kc++) a[kc] = *(const s16x8*)(arow + kc*8);
        }
        #pragma unroll
        for (int kc = 0; kc < 4; kc++) lsA[0][kc*256 + tid] = a[kc];
        float4 f0 = *(const float4*)(brow);
        float4 f1 = *(const float4*)(brow + 4);
        lsB[0][kcb*64 + rb] = cvt8(f0, f1);
    }
    s16x8 pa[4] = {{0},{0},{0},{0}};
    if (arow){
        #pragma unroll
        for (int kc = 0; kc < 4; kc++) pa[kc] = *(const s16x8*)(arow + BK + kc*8);
    }
    float4 pf0 = *(const float4*)(brow + BK);
    float4 pf1 = *(const float4*)(brow + BK + 4);

    int cur = 0;
    for (int k0 = 0; k0 < I_N; k0 += BK){
        __syncthreads();
        s16x8 na[4] = {{0},{0},{0},{0}};
        float4 nf0{}, nf1{};
        if (k0 + 2*BK < I_N){
            const int kn = k0 + 2*BK;
            if (arow){
                #pragma unroll
                for (int kc = 0; kc < 4; kc++) na[kc] = *(const s16x8*)(arow + kn + kc*8);
            }
            nf0 = *(const float4*)(brow + kn);
            nf1 = *(const float4*)(brow + kn + 4);
        }
        if (k0 + BK < I_N){
            const int nbuf = cur ^ 1;
            #pragma unroll
            for (int kc = 0; kc < 4; kc++) lsA[nbuf][kc*256 + tid] = pa[kc];
            lsB[nbuf][kcb*64 + rb] = cvt8(pf0, pf1);
        }
        #pragma unroll
        for (int mf = 0; mf < 4; mf++){
            s16x8 a = lsA[cur][kg*256 + wm*64 + mf*16 + l15];
            #pragma unroll
            for (int nf = 0; nf < 4; nf++){
                s16x8 b = lsB[cur][kg*64 + nf*16 + l15];
                acc[mf][nf] = __builtin_amdgcn_mfma_f32_16x16x32_bf16(a, b, acc[mf][nf], 0, 0, 0);
            }
        }
        #pragma unroll
        for (int kc = 0; kc < 4; kc++) pa[kc] = na[kc];
        pf0 = nf0; pf1 = nf1;
        cur ^= 1;
    }
    #pragma unroll
    for (int mf = 0; mf < 4; mf++){
        #pragma unroll
        for (int j = 0; j < 4; j++){
            int row = m0 + wm*64 + mf*16 + kg*4 + j;
            if (row < cnt){
                int aidx = off + row;
                if (USE_Y){
                    #pragma unroll
                    for (int nf = 0; nf < 4; nf++){
                        int col = n0 + nf*16 + l15;
                        y[(size_t)aidx * H_N + col] = f2bf(acc[mf][nf][j]);
                    }
                } else {
                    int tok = perm[aidx];
                    float w = wgt[aidx];
                    #pragma unroll
                    for (int nf = 0; nf < 4; nf++){
                        int col = n0 + nf*16 + l15;
                        atomicAdd(&out[(size_t)tok * H_N + col], w * acc[mf][nf][j]);
                    }
                }
            }
        }
    }
}

// ---------------- combine: out[t] = sum_k w*y[apos] + sig*y[shared] ----------------
__global__ __launch_bounds__(256) void combine_kernel(
    const short* __restrict__ y, const int* __restrict__ apos,
    const float* __restrict__ tw, const float* __restrict__ wgt,
    float* __restrict__ out)
{
    const int t = blockIdx.x;
    const int c0 = threadIdx.x * 8;
    float acc[8];
    {
        float ws = wgt[NA_MOE + t];
        s16x8 v = *(const s16x8*)(y + (size_t)(NA_MOE + t) * H_N + c0);
        #pragma unroll
        for (int j = 0; j < 8; j++) acc[j] = ws * bf2f(v[j]);
    }
    #pragma unroll
    for (int k = 0; k < 4; k++){
        int p   = apos[t*4 + k];
        float w = tw[t*4 + k];
        s16x8 v = *(const s16x8*)(y + (size_t)p * H_N + c0);
        #pragma unroll
        for (int j = 0; j < 8; j++) acc[j] += w * bf2f(v[j]);
    }
    float4 o0 = make_float4(acc[0], acc[1], acc[2], acc[3]);
    float4 o1 = make_float4(acc[4], acc[5], acc[6], acc[7]);
    *(float4*)(out + (size_t)t * H_N + c0)     = o0;
    *(float4*)(out + (size_t)t * H_N + c0 + 4) = o1;
}

extern "C" void kernel_launch(void* const* d_in, const int* in_sizes, int n_in,
                              void* d_out, int out_size, void* d_ws, size_t ws_size,
                              hipStream_t stream)
{
    const float* x      = (const float*)d_in[0];
    const float* Wr     = (const float*)d_in[1];
    const float* Wg     = (const float*)d_in[2];
    const float* Wu     = (const float*)d_in[3];
    const float* Wd     = (const float*)d_in[4];
    const float* Wsg    = (const float*)d_in[5];
    const float* Wsu    = (const float*)d_in[6];
    const float* Wsd    = (const float*)d_in[7];
    const float* Wsgate = (const float*)d_in[8];

    float* out    = (float*)d_out;
    float* logits = out + (size_t)T_N * H_N;

    char* ws = (char*)d_ws;
    short* xbf  = (short*)ws;                          // 8,388,608 B
    short* hact = (short*)(ws + 8388608);              // 10,485,760 B
    int*   perm = (int*)(ws + 18874368);               // 40,960
    float* wgt  = (float*)(ws + 18915328);             // 40,960
    int*   tidx = (int*)(ws + 18956288);               // 32,768
    float* tw   = (float*)(ws + 18989056);             // 32,768
    int*   apos = (int*)(ws + 19021824);               // 32,768
    int*   ctrl = (int*)(ws + 19054592);               // 2,048
    short* y    = (short*)(ws + 19056640);             // 41,943,040 -> ends 60,999,680
    float* part = (float*)(ws + 60999680);             // 83,886,080 -> ends 144,885,760
    const bool use_y    = (ws_size >= 60999680ull);
    const bool use_part = (ws_size >= 144885760ull);

    hipMemsetAsync(ctrl, 0, 256 * sizeof(int), stream);
    if (!use_y)
        hipMemsetAsync(d_out, 0, (size_t)T_N * H_N * sizeof(float), stream);

    cast_x_kernel<<<2048, 256, 0, stream>>>(x, xbf);
    router_kernel<<<T_N, 64, 0, stream>>>(x, Wr, Wsgate, logits, tidx, tw, perm, wgt, ctrl);
    scan_kernel<<<1, 64, 0, stream>>>(ctrl);
    scatter_kernel<<<T_N/256, 256, 0, stream>>>(tidx, tw, perm, wgt, apos, ctrl);
    if (use_part){
        gemm1_kernel<2><<<MAXT*32, 256, 0, stream>>>(xbf, Wg, Wu, Wsg, Wsu, perm, ctrl, hact, part);
        fixup_kernel<<<(NA_ALL*I_N)/(256*8), 256, 0, stream>>>(part, hact);
    } else {
        gemm1_kernel<1><<<MAXT*16, 256, 0, stream>>>(xbf, Wg, Wu, Wsg, Wsu, perm, ctrl, hact, part);
    }
    if (use_y){
        gemm2_kernel<1><<<MAXT*32, 256, 0, stream>>>(hact, Wd, Wsd, perm, wgt, ctrl, out, y);
        combine_kernel<<<T_N, 256, 0, stream>>>(y, apos, tw, wgt, out);
    } else {
        gemm2_kernel<0><<<MAXT*32, 256, 0, stream>>>(hact, Wd, Wsd, perm, wgt, ctrl, out, y);
    }
}

// Round 8
// 455.890 us; speedup vs baseline: 1.0460x; 1.0460x over previous
//
#include <hip/hip_runtime.h>
#include <math.h>

#define T_N 2048
#define H_N 2048
#define E_N 32
#define I_N 512
#define NA_MOE (T_N*4)        // 8192 routed assignments
#define NA_ALL (NA_MOE + T_N) // + shared-expert rows = 10240
#define BM 128
#define BK 32
#define MAXT 112              // sum ceil(cnt/128) <= 96 routed + 16 shared

typedef short s16x8 __attribute__((ext_vector_type(8)));
typedef float f32x4 __attribute__((ext_vector_type(4)));

typedef __attribute__((address_space(1))) unsigned int gu32;
typedef __attribute__((address_space(3))) unsigned int lu32;

__device__ inline void gload16(const void* g, void* l){
#if __has_builtin(__builtin_amdgcn_global_load_lds)
    __builtin_amdgcn_global_load_lds((gu32*)g, (lu32*)l, 16, 0, 0);
#else
    *(s16x8*)l = *(const s16x8*)g;
#endif
}

__device__ inline short f2bf(float f){          // native RNE cvt (v_cvt_pk_bf16_f32)
    return __builtin_bit_cast(short, (__bf16)f);
}
__device__ inline float bf2f(short s){
    return __uint_as_float(((unsigned int)(unsigned short)s) << 16);
}
__device__ inline s16x8 cvt8(float4 f0, float4 f1){
    s16x8 v;
    v[0]=f2bf(f0.x); v[1]=f2bf(f0.y); v[2]=f2bf(f0.z); v[3]=f2bf(f0.w);
    v[4]=f2bf(f1.x); v[5]=f2bf(f1.y); v[6]=f2bf(f1.z); v[7]=f2bf(f1.w);
    return v;
}

// ---------------- cast x (fp32 -> bf16) ----------------
__global__ __launch_bounds__(256) void cast_x_kernel(const float* __restrict__ x,
                                                     short* __restrict__ xbf){
    size_t i = (size_t)(blockIdx.x * 256 + threadIdx.x) * 8;
    float4 a = *(const float4*)(x + i);
    float4 b = *(const float4*)(x + i + 4);
    *(s16x8*)(xbf + i) = cvt8(a, b);
}

// ---------------- router: logits (fp64 acc), softmax, top4, shared gate ----------------
__global__ __launch_bounds__(64) void router_kernel(
    const float* __restrict__ x, const float* __restrict__ Wr,
    const float* __restrict__ Wsgate,
    float* __restrict__ logits_out, int* __restrict__ tidx, float* __restrict__ tw,
    int* __restrict__ perm, float* __restrict__ wgt, int* __restrict__ counts)
{
    const int t = blockIdx.x, lane = threadIdx.x;
    const float* xr = x + (size_t)t * H_N;
    float xv[32];
    #pragma unroll
    for (int i = 0; i < 32; i++) xv[i] = xr[i*64 + lane];
    __shared__ float lg[34];
    for (int e = 0; e < 33; e++){
        const float* wr = (e < 32) ? (Wr + (size_t)e * H_N) : Wsgate;
        double s = 0.0;
        #pragma unroll
        for (int i = 0; i < 32; i++) s += (double)xv[i] * (double)wr[i*64 + lane];
        #pragma unroll
        for (int o = 32; o > 0; o >>= 1) s += __shfl_down(s, o);
        if (lane == 0) lg[e] = (float)s;
    }
    __syncthreads();
    if (lane < 32) logits_out[(size_t)t*32 + lane] = lg[lane];
    if (lane == 0){
        float m = lg[0];
        for (int e = 1; e < 32; e++) m = fmaxf(m, lg[e]);
        unsigned mask = 0; int sel[4]; float sv[4]; float s4 = 0.f;
        for (int k = 0; k < 4; k++){
            int best = -1; float bv = -1e30f;
            for (int e = 0; e < 32; e++)
                if (!((mask >> e) & 1u) && lg[e] > bv){ bv = lg[e]; best = e; }
            mask |= 1u << best; sel[k] = best;
            float p = expf(lg[best] - m); sv[k] = p; s4 += p;
        }
        for (int k = 0; k < 4; k++){
            tidx[t*4 + k] = sel[k];
            tw[t*4 + k]   = sv[k] / s4;
            atomicAdd(&counts[sel[k]], 1);
        }
        perm[NA_MOE + t] = t;                       // shared expert row
        wgt[NA_MOE + t]  = 1.f / (1.f + expf(-lg[32]));
    }
}

// ---------------- scan: offsets + worklist (shared expert first) ----------------
// ctrl ints: [0..63] counts, [64..127] cursors, [128..191] eoff,
//            [192..255] ecnt, [256] ntiles, [260..371] worklist
__global__ void scan_kernel(int* ctrl){
    if (threadIdx.x == 0){
        int* counts = ctrl; int* eoff = ctrl + 128; int* ecnt = ctrl + 192;
        int acc = 0;
        for (int e = 0; e < 32; e++){ eoff[e] = acc; ecnt[e] = counts[e]; acc += counts[e]; }
        eoff[32] = NA_MOE; ecnt[32] = T_N;
        int nt = 0;
        for (int m = 0; m * BM < T_N; m++) ctrl[260 + nt++] = (32 << 16) | m;   // shared first
        for (int e = 0; e < 32; e++){
            int c = ecnt[e];
            for (int m = 0; m * BM < c; m++) ctrl[260 + nt++] = (e << 16) | m;
        }
        ctrl[256] = nt;
    }
    if (threadIdx.x < 64) ctrl[64 + threadIdx.x] = 0;  // cursors
}

// ---------------- scatter tokens into per-expert lists ----------------
__global__ __launch_bounds__(256) void scatter_kernel(
    const int* __restrict__ tidx, const float* __restrict__ tw,
    int* __restrict__ perm, float* __restrict__ wgt, int* __restrict__ apos,
    int* ctrl)
{
    int t = blockIdx.x * 256 + threadIdx.x;
    if (t >= T_N) return;
    const int* eoff = ctrl + 128; int* cursor = ctrl + 64;
    for (int k = 0; k < 4; k++){
        int e = tidx[t*4 + k];
        int pos = eoff[e] + atomicAdd(&cursor[e], 1);
        perm[pos] = t; wgt[pos] = tw[t*4 + k]; apos[t*4 + k] = pos;
    }
}

// ---------------- GEMM1: 128x64 tile, A via global_load_lds, B reg depth-2 ----------------
__global__ __launch_bounds__(256, 3) void gemm1_kernel(
    const short* __restrict__ xbf,
    const float* __restrict__ Wg, const float* __restrict__ Wu,
    const float* __restrict__ Wsg, const float* __restrict__ Wsu,
    const int* __restrict__ perm, const int* __restrict__ ctrl,
    short* __restrict__ hact)
{
    const int tile = blockIdx.x >> 3;
    if (tile >= ctrl[256]) return;
    const int wrk = ctrl[260 + tile];
    const int e   = wrk >> 16;
    const int m0  = (wrk & 0xffff) << 7;
    const int cnt = ctrl[192 + e];
    const int off = ctrl[128 + e];
    const int n0  = (blockIdx.x & 7) << 6;

    __shared__ s16x8 lsA[2][4*128];   // [buf][kc][row], 16 KB
    __shared__ s16x8 lsBg[2][4*64];   // [buf][chunk],   8 KB
    __shared__ s16x8 lsBu[2][4*64];   //                 8 KB

    const int tid = threadIdx.x;
    // A: row r_a, chunks kca and kca+2 (clamped row index -> always valid)
    const int r_a = tid & 127;
    const int kca = tid >> 7;      // 0/1
    int srow = off + ((m0 + r_a < cnt) ? (m0 + r_a) : (cnt - 1));
    const short* arow = xbf + (size_t)perm[srow] * H_N;

    // B: linear chunk map (chunk = tid), each thread stages one g and one u chunk
    const int rb = tid & 63, kcb = tid >> 6;
    const float *browg, *browu;
    if (e < 32){
        browg = Wg + ((size_t)e * I_N + (n0 + rb)) * H_N + kcb*8;
        browu = Wu + ((size_t)e * I_N + (n0 + rb)) * H_N + kcb*8;
    } else {
        browg = Wsg + (size_t)(n0 + rb) * H_N + kcb*8;
        browu = Wsu + (size_t)(n0 + rb) * H_N + kcb*8;
    }

    const int wid = tid >> 6, lane = tid & 63;
    const int wm = wid >> 1, wn = wid & 1;       // 2m x 2n waves
    const int kg = lane >> 4, l15 = lane & 15;

    f32x4 accg[4][2], accu[4][2];
    #pragma unroll
    for (int a = 0; a < 4; a++)
        #pragma unroll
        for (int b = 0; b < 2; b++)
            #pragma unroll
            for (int j = 0; j < 4; j++){ accg[a][b][j] = 0.f; accu[a][b][j] = 0.f; }

    // prologue: A(0) -> lds[0] via gload; B(0) regs -> lds[0]; pending = B(1)
    gload16(arow + kca*8,        &lsA[0][kca*128 + r_a]);
    gload16(arow + (kca+2)*8,    &lsA[0][(kca+2)*128 + r_a]);
    {
        float4 g0 = *(const float4*)(browg);
        float4 g1 = *(const float4*)(browg + 4);
        float4 u0 = *(const float4*)(browu);
        float4 u1 = *(const float4*)(browu + 4);
        lsBg[0][tid] = cvt8(g0, g1);
        lsBu[0][tid] = cvt8(u0, u1);
    }
    float4 pg0 = *(const float4*)(browg + BK);
    float4 pg1 = *(const float4*)(browg + BK + 4);
    float4 pu0 = *(const float4*)(browu + BK);
    float4 pu1 = *(const float4*)(browu + BK + 4);

    int cur = 0;
    for (int k0 = 0; k0 < H_N; k0 += BK){
        __syncthreads();                           // buf[cur] ready
        const int nbuf = cur ^ 1;
        if (k0 + BK < H_N){
            gload16(arow + k0 + BK + kca*8,     &lsA[nbuf][kca*128 + r_a]);
            gload16(arow + k0 + BK + (kca+2)*8, &lsA[nbuf][(kca+2)*128 + r_a]);
            lsBg[nbuf][tid] = cvt8(pg0, pg1);
            lsBu[nbuf][tid] = cvt8(pu0, pu1);
        }
        if (k0 + 2*BK < H_N){                      // B regs for k+2
            const int kn = k0 + 2*BK;
            pg0 = *(const float4*)(browg + kn);
            pg1 = *(const float4*)(browg + kn + 4);
            pu0 = *(const float4*)(browu + kn);
            pu1 = *(const float4*)(browu + kn + 4);
        }
        #pragma unroll
        for (int mf = 0; mf < 4; mf++){
            s16x8 a = lsA[cur][kg*128 + wm*64 + mf*16 + l15];
            #pragma unroll
            for (int nf = 0; nf < 2; nf++){
                s16x8 bg = lsBg[cur][kg*64 + wn*32 + nf*16 + l15];
                s16x8 bu = lsBu[cur][kg*64 + wn*32 + nf*16 + l15];
                accg[mf][nf] = __builtin_amdgcn_mfma_f32_16x16x32_bf16(a, bg, accg[mf][nf], 0, 0, 0);
                accu[mf][nf] = __builtin_amdgcn_mfma_f32_16x16x32_bf16(a, bu, accu[mf][nf], 0, 0, 0);
            }
        }
        cur ^= 1;
    }
    #pragma unroll
    for (int mf = 0; mf < 4; mf++){
        #pragma unroll
        for (int j = 0; j < 4; j++){
            int row = m0 + wm*64 + mf*16 + kg*4 + j;
            if (row < cnt){
                #pragma unroll
                for (int nf = 0; nf < 2; nf++){
                    int col = n0 + wn*32 + nf*16 + l15;
                    float g = accg[mf][nf][j], u = accu[mf][nf][j];
                    float h = g / (1.f + expf(-g)) * u;
                    hact[(size_t)(off + row) * I_N + col] = f2bf(h);
                }
            }
        }
    }
}

// ---------------- GEMM2: 128x64 tile, A via global_load_lds, B reg depth-2 ----------------
template<int USE_Y>
__global__ __launch_bounds__(256, 3) void gemm2_kernel(
    const short* __restrict__ hact,
    const float* __restrict__ Wd, const float* __restrict__ Wsd,
    const int* __restrict__ perm, const float* __restrict__ wgt,
    const int* __restrict__ ctrl, float* __restrict__ out, short* __restrict__ y)
{
    const int tile = blockIdx.x >> 5;
    if (tile >= ctrl[256]) return;
    const int wrk = ctrl[260 + tile];
    const int e   = wrk >> 16;
    const int m0  = (wrk & 0xffff) << 7;
    const int cnt = ctrl[192 + e];
    const int off = ctrl[128 + e];
    const int n0  = (blockIdx.x & 31) << 6;

    __shared__ s16x8 lsA[2][4*128];
    __shared__ s16x8 lsB[2][4*64];

    const int tid = threadIdx.x;
    const int r_a = tid & 127;
    const int kca = tid >> 7;
    int srow = off + ((m0 + r_a < cnt) ? (m0 + r_a) : (cnt - 1));
    const short* arow = hact + (size_t)srow * I_N;

    const int rb = tid & 63, kcb = tid >> 6;
    const float* brow = (e < 32) ? (Wd  + ((size_t)e * H_N + n0 + rb) * I_N + kcb*8)
                                 : (Wsd + (size_t)(n0 + rb) * I_N + kcb*8);

    const int wid = tid >> 6, lane = tid & 63;
    const int wm = wid >> 1, wn = wid & 1;
    const int kg = lane >> 4, l15 = lane & 15;

    f32x4 acc[4][2];
    #pragma unroll
    for (int a = 0; a < 4; a++)
        #pragma unroll
        for (int b = 0; b < 2; b++)
            #pragma unroll
            for (int j = 0; j < 4; j++) acc[a][b][j] = 0.f;

    gload16(arow + kca*8,     &lsA[0][kca*128 + r_a]);
    gload16(arow + (kca+2)*8, &lsA[0][(kca+2)*128 + r_a]);
    {
        float4 f0 = *(const float4*)(brow);
        float4 f1 = *(const float4*)(brow + 4);
        lsB[0][tid] = cvt8(f0, f1);
    }
    float4 pf0 = *(const float4*)(brow + BK);
    float4 pf1 = *(const float4*)(brow + BK + 4);

    int cur = 0;
    for (int k0 = 0; k0 < I_N; k0 += BK){
        __syncthreads();
        const int nbuf = cur ^ 1;
        if (k0 + BK < I_N){
            gload16(arow + k0 + BK + kca*8,     &lsA[nbuf][kca*128 + r_a]);
            gload16(arow + k0 + BK + (kca+2)*8, &lsA[nbuf][(kca+2)*128 + r_a]);
            lsB[nbuf][tid] = cvt8(pf0, pf1);
        }
        if (k0 + 2*BK < I_N){
            const int kn = k0 + 2*BK;
            pf0 = *(const float4*)(brow + kn);
            pf1 = *(const float4*)(brow + kn + 4);
        }
        #pragma unroll
        for (int mf = 0; mf < 4; mf++){
            s16x8 a = lsA[cur][kg*128 + wm*64 + mf*16 + l15];
            #pragma unroll
            for (int nf = 0; nf < 2; nf++){
                s16x8 b = lsB[cur][kg*64 + wn*32 + nf*16 + l15];
                acc[mf][nf] = __builtin_amdgcn_mfma_f32_16x16x32_bf16(a, b, acc[mf][nf], 0, 0, 0);
            }
        }
        cur ^= 1;
    }
    #pragma unroll
    for (int mf = 0; mf < 4; mf++){
        #pragma unroll
        for (int j = 0; j < 4; j++){
            int row = m0 + wm*64 + mf*16 + kg*4 + j;
            if (row < cnt){
                int aidx = off + row;
                if (USE_Y){
                    #pragma unroll
                    for (int nf = 0; nf < 2; nf++){
                        int col = n0 + wn*32 + nf*16 + l15;
                        y[(size_t)aidx * H_N + col] = f2bf(acc[mf][nf][j]);
                    }
                } else {
                    int tok = perm[aidx];
                    float w = wgt[aidx];
                    #pragma unroll
                    for (int nf = 0; nf < 2; nf++){
                        int col = n0 + wn*32 + nf*16 + l15;
                        atomicAdd(&out[(size_t)tok * H_N + col], w * acc[mf][nf][j]);
                    }
                }
            }
        }
    }
}

// ---------------- combine: out[t] = sum_k w*y[apos] + sig*y[shared] ----------------
__global__ __launch_bounds__(256) void combine_kernel(
    const short* __restrict__ y, const int* __restrict__ apos,
    const float* __restrict__ tw, const float* __restrict__ wgt,
    float* __restrict__ out)
{
    const int t = blockIdx.x;
    const int c0 = threadIdx.x * 8;
    float acc[8];
    {
        float ws = wgt[NA_MOE + t];
        s16x8 v = *(const s16x8*)(y + (size_t)(NA_MOE + t) * H_N + c0);
        #pragma unroll
        for (int j = 0; j < 8; j++) acc[j] = ws * bf2f(v[j]);
    }
    #pragma unroll
    for (int k = 0; k < 4; k++){
        int p   = apos[t*4 + k];
        float w = tw[t*4 + k];
        s16x8 v = *(const s16x8*)(y + (size_t)p * H_N + c0);
        #pragma unroll
        for (int j = 0; j < 8; j++) acc[j] += w * bf2f(v[j]);
    }
    float4 o0 = make_float4(acc[0], acc[1], acc[2], acc[3]);
    float4 o1 = make_float4(acc[4], acc[5], acc[6], acc[7]);
    *(float4*)(out + (size_t)t * H_N + c0)     = o0;
    *(float4*)(out + (size_t)t * H_N + c0 + 4) = o1;
}

extern "C" void kernel_launch(void* const* d_in, const int* in_sizes, int n_in,
                              void* d_out, int out_size, void* d_ws, size_t ws_size,
                              hipStream_t stream)
{
    const float* x      = (const float*)d_in[0];
    const float* Wr     = (const float*)d_in[1];
    const float* Wg     = (const float*)d_in[2];
    const float* Wu     = (const float*)d_in[3];
    const float* Wd     = (const float*)d_in[4];
    const float* Wsg    = (const float*)d_in[5];
    const float* Wsu    = (const float*)d_in[6];
    const float* Wsd    = (const float*)d_in[7];
    const float* Wsgate = (const float*)d_in[8];

    float* out    = (float*)d_out;
    float* logits = out + (size_t)T_N * H_N;

    char* ws = (char*)d_ws;
    short* xbf  = (short*)ws;                          // 8,388,608 B
    short* hact = (short*)(ws + 8388608);              // 10,485,760 B
    int*   perm = (int*)(ws + 18874368);               // 40,960
    float* wgt  = (float*)(ws + 18915328);             // 40,960
    int*   tidx = (int*)(ws + 18956288);               // 32,768
    float* tw   = (float*)(ws + 18989056);             // 32,768
    int*   apos = (int*)(ws + 19021824);               // 32,768
    int*   ctrl = (int*)(ws + 19054592);               // 2,048
    short* y    = (short*)(ws + 19056640);             // 41,943,040 -> ends 60,999,680
    const bool use_y = (ws_size >= 60999680ull);

    hipMemsetAsync(ctrl, 0, 256 * sizeof(int), stream);
    if (!use_y)
        hipMemsetAsync(d_out, 0, (size_t)T_N * H_N * sizeof(float), stream);

    cast_x_kernel<<<2048, 256, 0, stream>>>(x, xbf);
    router_kernel<<<T_N, 64, 0, stream>>>(x, Wr, Wsgate, logits, tidx, tw, perm, wgt, ctrl);
    scan_kernel<<<1, 64, 0, stream>>>(ctrl);
    scatter_kernel<<<T_N/256, 256, 0, stream>>>(tidx, tw, perm, wgt, apos, ctrl);
    gemm1_kernel<<<MAXT*8, 256, 0, stream>>>(xbf, Wg, Wu, Wsg, Wsu, perm, ctrl, hact);
    if (use_y){
        gemm2_kernel<1><<<MAXT*32, 256, 0, stream>>>(hact, Wd, Wsd, perm, wgt, ctrl, out, y);
        combine_kernel<<<T_N, 256, 0, stream>>>(y, apos, tw, wgt, out);
    } else {
        gemm2_kernel<0><<<MAXT*32, 256, 0, stream>>>(hact, Wd, Wsd, perm, wgt, ctrl, out, y);
    }
}